// Round 3
// baseline (919.598 us; speedup 1.0000x reference)
//
#include <hip/hip_runtime.h>
#include <hip/hip_bf16.h>

#define GRID_R  256
#define GRID_RR 65536   // 256*256

// One thread per ray. fp32 inputs, fp32 math, fp32 output.
// Computes the 3 trilinearly-interpolated finite-difference normals
// (+ (1-mask) corner offset) and relu(-grid)*mask at the base corner.
__global__ __launch_bounds__(256) void sdf_grid_kernel(
    const float* __restrict__ grid,
    const int*   __restrict__ vidx,
    const float* __restrict__ ipos,
    const float* __restrict__ vmin,
    const int*   __restrict__ mask,
    float*       __restrict__ out,
    int n)
{
    const float INV_VS  = 63.75f;   // 1/VOXEL_SIZE  = 255/4 (exact)
    const float INV_2VS = 31.875f;  // 1/(2*VOXEL_SIZE) = 255/8 (exact)

    int i = blockIdx.x * blockDim.x + threadIdx.x;
    if (i >= n) return;

    int x = vidx[3*i+0];
    int y = vidx[3*i+1];
    int z = vidx[3*i+2];

    float tx = (ipos[3*i+0] - vmin[3*i+0]) * INV_VS;
    float ty = (ipos[3*i+1] - vmin[3*i+1]) * INV_VS;
    float tz = (ipos[3*i+2] - vmin[3*i+2]) * INV_VS;

    int   m   = mask[i];
    float inv = 1.0f - (float)m;   // added to all 8 corner values pre-weighting

    float ox = 1.0f - tx, oy = 1.0f - ty, oz = 1.0f - tz;
    // corner order: dx outer, dy mid, dz inner (matches CORNERS / weight list)
    float w[8];
    w[0] = oz*oy*ox;  w[1] = tz*oy*ox;  w[2] = oz*ty*ox;  w[3] = tz*ty*ox;
    w[4] = oz*oy*tx;  w[5] = tz*oy*tx;  w[6] = oz*ty*tx;  w[7] = tz*ty*tx;

    int base = z + GRID_R*y + GRID_RR*x;

    float nout[3];
    #pragma unroll
    for (int a = 0; a < 3; ++a) {
        const int s  = (a==0) ? GRID_RR : (a==1) ? GRID_R : 1;
        const int c0 = (a==0) ? x : (a==1) ? y : z;
        float acc = 0.0f;
        #pragma unroll
        for (int k = 0; k < 8; ++k) {
            const int dx = k>>2, dy = (k>>1)&1, dz = k&1;
            const int b  = base + dz + GRID_R*dy + GRID_RR*dx;
            const int c  = c0 + ((a==0) ? dx : (a==1) ? dy : dz);
            float v;
            if (c == 0) {
                // fwd = g1 ; bwd = (3*g0 - g2)/2
                v = grid[b+s] - (3.0f*grid[b] - grid[b+2*s])*0.5f;
            } else if (c == GRID_R-1) {
                // fwd = (3*g255 - g253)/2 ; bwd = g254
                v = (3.0f*grid[b] - grid[b-2*s])*0.5f - grid[b-s];
            } else {
                v = grid[b+s] - grid[b-s];
            }
            acc += (v*INV_2VS + inv) * w[k];
        }
        nout[a] = acc;
    }

    float g0 = grid[base];
    float gx = fmaxf(-g0, 0.0f) * (float)m;

    float4 o;
    o.x = nout[0];
    o.y = nout[1];
    o.z = nout[2];
    o.w = gx;
    *reinterpret_cast<float4*>(out + 4*i) = o;
}

extern "C" void kernel_launch(void* const* d_in, const int* in_sizes, int n_in,
                              void* d_out, int out_size, void* d_ws, size_t ws_size,
                              hipStream_t stream) {
    const float* grid = (const float*)d_in[0];
    const int*   vidx = (const int*)d_in[1];
    const float* ipos = (const float*)d_in[2];
    const float* vmin = (const float*)d_in[3];
    const int*   mask = (const int*)d_in[4];
    float*       out  = (float*)d_out;

    const int n = in_sizes[4];          // H*W rays (mask element count)
    const int block = 256;
    const int gridsz = (n + block - 1) / block;
    sdf_grid_kernel<<<gridsz, block, 0, stream>>>(grid, vidx, ipos, vmin, mask, out, n);
}

// Round 4
// 300.751 us; speedup vs baseline: 3.0577x; 3.0577x over previous
//
#include <hip/hip_runtime.h>
#include <hip/hip_bf16.h>

#define GRID_R  256
#define GRID_RR 65536        // 256*256
#define NVOX    16777216     // 256^3

__device__ __forceinline__ float h2f(unsigned short u) {
    union { unsigned short s; _Float16 f; } cv; cv.s = u; return (float)cv.f;
}
__device__ __forceinline__ unsigned short f2h(float x) {
    union { unsigned short s; _Float16 f; } cv; cv.f = (_Float16)x; return cv.s;
}

// ---------------- pre-pass: packed[v] = half4(nx, ny, nz, g) ----------------
// normal = (fwd - bwd)/(2*vs); interior central diff, one-sided extrapolated
// boundary exactly as the reference:
//   c==0:   fwd=g1,               bwd=(3*g0-g2)/2  -> (g1 - 1.5 g0 + 0.5 g2)/(2vs)
//   c==255: fwd=(3*g255-g253)/2,  bwd=g254         -> (1.5 g255 - 0.5 g253 - g254)/(2vs)
__device__ __forceinline__ float axis_normal(const float* __restrict__ g,
                                             int v, int c, int s, float g0) {
    const float INV_2VS = 31.875f;  // 255/8 exact
    if (c == 0)            return (g[v+s] - 1.5f*g0 + 0.5f*g[v+2*s]) * INV_2VS;
    else if (c == GRID_R-1) return (1.5f*g0 - 0.5f*g[v-2*s] - g[v-s]) * INV_2VS;
    else                   return (g[v+s] - g[v-s]) * INV_2VS;
}

__global__ __launch_bounds__(256) void precompute_kernel(
    const float* __restrict__ grid,
    uint2*       __restrict__ packed)
{
    int v = blockIdx.x * blockDim.x + threadIdx.x;
    if (v >= NVOX) return;
    int z = v & 255, y = (v >> 8) & 255, x = v >> 16;
    float g0 = grid[v];
    float nx = axis_normal(grid, v, x, GRID_RR, g0);
    float ny = axis_normal(grid, v, y, GRID_R,  g0);
    float nz = axis_normal(grid, v, z, 1,       g0);
    uint2 p;
    p.x = (unsigned)f2h(nx) | ((unsigned)f2h(ny) << 16);
    p.y = (unsigned)f2h(nz) | ((unsigned)f2h(g0) << 16);
    packed[v] = p;
}

// ---------------- gather pass: one thread per ray ----------------
__global__ __launch_bounds__(256) void gather_kernel(
    const uint2* __restrict__ packed,
    const int*   __restrict__ vidx,
    const float* __restrict__ ipos,
    const float* __restrict__ vmin,
    const int*   __restrict__ mask,
    float*       __restrict__ out,
    int n)
{
    const float INV_VS = 63.75f;   // 255/4 exact

    int i = blockIdx.x * blockDim.x + threadIdx.x;
    if (i >= n) return;

    int x = vidx[3*i+0];
    int y = vidx[3*i+1];
    int z = vidx[3*i+2];

    float tx = (ipos[3*i+0] - vmin[3*i+0]) * INV_VS;
    float ty = (ipos[3*i+1] - vmin[3*i+1]) * INV_VS;
    float tz = (ipos[3*i+2] - vmin[3*i+2]) * INV_VS;

    int   m   = mask[i];
    float inv = 1.0f - (float)m;

    float ox = 1.0f - tx, oy = 1.0f - ty, oz = 1.0f - tz;
    // corner order k = dx*4 + dy*2 + dz (dx outer, dz inner) — matches reference
    float w[8];
    w[0] = oz*oy*ox;  w[1] = tz*oy*ox;  w[2] = oz*ty*ox;  w[3] = tz*ty*ox;
    w[4] = oz*oy*tx;  w[5] = tz*oy*tx;  w[6] = oz*ty*tx;  w[7] = tz*ty*tx;

    int base = z + GRID_R*y + GRID_RR*x;

    float accx = 0.f, accy = 0.f, accz = 0.f;
    float gbase = 0.f;

    #pragma unroll
    for (int dx = 0; dx < 2; ++dx) {
        #pragma unroll
        for (int dy = 0; dy < 2; ++dy) {
            int b = base + GRID_RR*dx + GRID_R*dy;
            uint2 p0 = packed[b];       // dz = 0
            uint2 p1 = packed[b + 1];   // dz = 1
            int k = dx*4 + dy*2;
            accx += h2f(p0.x & 0xffff)  * w[k] + h2f(p1.x & 0xffff)  * w[k+1];
            accy += h2f(p0.x >> 16)     * w[k] + h2f(p1.x >> 16)     * w[k+1];
            accz += h2f(p0.y & 0xffff)  * w[k] + h2f(p1.y & 0xffff)  * w[k+1];
            if (dx == 0 && dy == 0) gbase = h2f(p0.y >> 16);
        }
    }

    float4 o;
    o.x = accx + inv;   // + (1-m) on all 8 corners distributes out (sum w = 1)
    o.y = accy + inv;
    o.z = accz + inv;
    o.w = fmaxf(-gbase, 0.0f) * (float)m;
    *reinterpret_cast<float4*>(out + 4*i) = o;
}

// ---------------- fallback: direct on-the-fly kernel (round-3 version) ------
__global__ __launch_bounds__(256) void sdf_grid_kernel(
    const float* __restrict__ grid,
    const int*   __restrict__ vidx,
    const float* __restrict__ ipos,
    const float* __restrict__ vmin,
    const int*   __restrict__ mask,
    float*       __restrict__ out,
    int n)
{
    const float INV_VS  = 63.75f;
    const float INV_2VS = 31.875f;

    int i = blockIdx.x * blockDim.x + threadIdx.x;
    if (i >= n) return;

    int x = vidx[3*i+0], y = vidx[3*i+1], z = vidx[3*i+2];
    float tx = (ipos[3*i+0] - vmin[3*i+0]) * INV_VS;
    float ty = (ipos[3*i+1] - vmin[3*i+1]) * INV_VS;
    float tz = (ipos[3*i+2] - vmin[3*i+2]) * INV_VS;
    int   m   = mask[i];
    float inv = 1.0f - (float)m;
    float ox = 1.0f - tx, oy = 1.0f - ty, oz = 1.0f - tz;
    float w[8];
    w[0] = oz*oy*ox;  w[1] = tz*oy*ox;  w[2] = oz*ty*ox;  w[3] = tz*ty*ox;
    w[4] = oz*oy*tx;  w[5] = tz*oy*tx;  w[6] = oz*ty*tx;  w[7] = tz*ty*tx;
    int base = z + GRID_R*y + GRID_RR*x;
    float nout[3];
    #pragma unroll
    for (int a = 0; a < 3; ++a) {
        const int s  = (a==0) ? GRID_RR : (a==1) ? GRID_R : 1;
        const int c0 = (a==0) ? x : (a==1) ? y : z;
        float acc = 0.0f;
        #pragma unroll
        for (int k = 0; k < 8; ++k) {
            const int dx = k>>2, dy = (k>>1)&1, dz = k&1;
            const int b  = base + dz + GRID_R*dy + GRID_RR*dx;
            const int c  = c0 + ((a==0) ? dx : (a==1) ? dy : dz);
            float v;
            if (c == 0)            v = grid[b+s] - (3.0f*grid[b] - grid[b+2*s])*0.5f;
            else if (c == GRID_R-1) v = (3.0f*grid[b] - grid[b-2*s])*0.5f - grid[b-s];
            else                   v = grid[b+s] - grid[b-s];
            acc += (v*INV_2VS + inv) * w[k];
        }
        nout[a] = acc;
    }
    float gx = fmaxf(-grid[base], 0.0f) * (float)m;
    float4 o; o.x = nout[0]; o.y = nout[1]; o.z = nout[2]; o.w = gx;
    *reinterpret_cast<float4*>(out + 4*i) = o;
}

extern "C" void kernel_launch(void* const* d_in, const int* in_sizes, int n_in,
                              void* d_out, int out_size, void* d_ws, size_t ws_size,
                              hipStream_t stream) {
    const float* grid = (const float*)d_in[0];
    const int*   vidx = (const int*)d_in[1];
    const float* ipos = (const float*)d_in[2];
    const float* vmin = (const float*)d_in[3];
    const int*   mask = (const int*)d_in[4];
    float*       out  = (float*)d_out;

    const int n = in_sizes[4];          // H*W rays
    const int block = 256;

    if (ws_size >= (size_t)NVOX * 8) {
        uint2* packed = (uint2*)d_ws;
        precompute_kernel<<<NVOX / block, block, 0, stream>>>(grid, packed);
        gather_kernel<<<(n + block - 1) / block, block, 0, stream>>>(
            packed, vidx, ipos, vmin, mask, out, n);
    } else {
        sdf_grid_kernel<<<(n + block - 1) / block, block, 0, stream>>>(
            grid, vidx, ipos, vmin, mask, out, n);
    }
}

// Round 5
// 256.904 us; speedup vs baseline: 3.5795x; 1.1707x over previous
//
#include <hip/hip_runtime.h>
#include <hip/hip_bf16.h>

#define GRID_R   256
#define GRID_RR  65536       // 256*256
#define NVOX     16777216    // 256^3
#define NBRK     128         // bricks per axis
#define INV_2VS  31.875f     // 255/8 exact
#define INV_VS   63.75f      // 255/4 exact

__device__ __forceinline__ float h2f(unsigned short u) {
    union { unsigned short s; _Float16 f; } cv; cv.s = u; return (float)cv.f;
}
__device__ __forceinline__ unsigned f2h2(float a, float b) {  // pack two halves
    union { unsigned short s; _Float16 f; } ca, cb;
    ca.f = (_Float16)a; cb.f = (_Float16)b;
    return (unsigned)ca.s | ((unsigned)cb.s << 16);
}

// Reference boundary normals:
//   c==0:   (g1 - 1.5*g0 + 0.5*g2) * INV_2VS
//   c==255: (1.5*g255 - 0.5*g253 - g254) * INV_2VS
//   else:   (g[c+1] - g[c-1]) * INV_2VS

// ---------------- pre-pass: one thread per 2x2x2 brick -----------------------
// packed brick layout: 64 B/brick = 8 slots (uint2), slot s = dx*4+dy*2+dz,
// brick B = (bx*128 + by)*128 + bz.
__global__ __launch_bounds__(256) void precompute_brick_kernel(
    const float* __restrict__ grid,
    uint2*       __restrict__ packed)
{
    // bid: bx outer (changes every 64 blocks), by sweeps, bz = lane
    int bid = blockIdx.x;
    int t   = threadIdx.x;
    int bz  = t & 127;
    int by  = ((bid & 63) << 1) + (t >> 7);
    int bx  = bid >> 6;

    int x0 = bx << 1, y0 = by << 1, z0 = bz << 1;
    int x1 = x0 + 1, y1 = y0 + 1, z1 = z0 + 1;

    // clamped halo coords (clamped values are never used in the formulas)
    int xm = (x0 == 0) ? 0 : x0 - 1;          int xp = (x1 == 255) ? 255 : x1 + 1;
    int ym = (y0 == 0) ? 0 : y0 - 1;          int yp = (y1 == 255) ? 255 : y1 + 1;
    int zm = (z0 == 0) ? 0 : z0 - 1;          int zp = (z1 == 255) ? 255 : z1 + 1;

    #define G2(X,Y,Z) (*reinterpret_cast<const float2*>(grid + (((X)*GRID_R + (Y)) << 8) + (Z)))
    #define G1(X,Y,Z) (grid[(((X)*GRID_R + (Y)) << 8) + (Z)])

    float2 c00 = G2(x0, y0, z0), c01 = G2(x0, y1, z0);
    float2 c10 = G2(x1, y0, z0), c11 = G2(x1, y1, z0);
    float c[2][2][2] = {{{c00.x, c00.y}, {c01.x, c01.y}},
                        {{c10.x, c10.y}, {c11.x, c11.y}}};

    float2 xl0 = G2(xm, y0, z0), xl1 = G2(xm, y1, z0);
    float2 xh0 = G2(xp, y0, z0), xh1 = G2(xp, y1, z0);
    float xlo[2][2] = {{xl0.x, xl0.y}, {xl1.x, xl1.y}};   // [dy][dz]
    float xhi[2][2] = {{xh0.x, xh0.y}, {xh1.x, xh1.y}};

    float2 yl0 = G2(x0, ym, z0), yl1 = G2(x1, ym, z0);
    float2 yh0 = G2(x0, yp, z0), yh1 = G2(x1, yp, z0);
    float ylo[2][2] = {{yl0.x, yl0.y}, {yl1.x, yl1.y}};   // [dx][dz]
    float yhi[2][2] = {{yh0.x, yh0.y}, {yh1.x, yh1.y}};

    float zlo[2][2], zhi[2][2];                           // [dx][dy]
    zlo[0][0] = G1(x0, y0, zm); zlo[0][1] = G1(x0, y1, zm);
    zlo[1][0] = G1(x1, y0, zm); zlo[1][1] = G1(x1, y1, zm);
    zhi[0][0] = G1(x0, y0, zp); zhi[0][1] = G1(x0, y1, zp);
    zhi[1][0] = G1(x1, y0, zp); zhi[1][1] = G1(x1, y1, zp);
    #undef G2
    #undef G1

    bool xb0 = (x0 == 0), xb1 = (x1 == 255);
    bool yb0 = (y0 == 0), yb1 = (y1 == 255);
    bool zb0 = (z0 == 0), zb1 = (z1 == 255);

    uint2 slot[8];
    #pragma unroll
    for (int dx = 0; dx < 2; ++dx)
    #pragma unroll
    for (int dy = 0; dy < 2; ++dy)
    #pragma unroll
    for (int dz = 0; dz < 2; ++dz) {
        float g0 = c[dx][dy][dz];

        float nx;
        if (xb0 && dx == 0)      nx = (c[1][dy][dz] - 1.5f*g0 + 0.5f*xhi[dy][dz]) * INV_2VS;
        else if (xb1 && dx == 1) nx = (1.5f*g0 - 0.5f*xlo[dy][dz] - c[0][dy][dz]) * INV_2VS;
        else nx = ((dx ? xhi[dy][dz] : c[1][dy][dz]) - (dx ? c[0][dy][dz] : xlo[dy][dz])) * INV_2VS;

        float ny;
        if (yb0 && dy == 0)      ny = (c[dx][1][dz] - 1.5f*g0 + 0.5f*yhi[dx][dz]) * INV_2VS;
        else if (yb1 && dy == 1) ny = (1.5f*g0 - 0.5f*ylo[dx][dz] - c[dx][0][dz]) * INV_2VS;
        else ny = ((dy ? yhi[dx][dz] : c[dx][1][dz]) - (dy ? c[dx][0][dz] : ylo[dx][dz])) * INV_2VS;

        float nz;
        if (zb0 && dz == 0)      nz = (c[dx][dy][1] - 1.5f*g0 + 0.5f*zhi[dx][dy]) * INV_2VS;
        else if (zb1 && dz == 1) nz = (1.5f*g0 - 0.5f*zlo[dx][dy] - c[dx][dy][0]) * INV_2VS;
        else nz = ((dz ? zhi[dx][dy] : c[dx][dy][1]) - (dz ? c[dx][dy][0] : zlo[dx][dy])) * INV_2VS;

        int s = dx*4 + dy*2 + dz;
        slot[s].x = f2h2(nx, ny);
        slot[s].y = f2h2(nz, g0);
    }

    long long B = ((long long)(bx*NBRK + by))*NBRK + bz;
    uint4* dst = reinterpret_cast<uint4*>(packed) + B*4;
    #pragma unroll
    for (int j = 0; j < 4; ++j) {
        uint4 st; st.x = slot[2*j].x; st.y = slot[2*j].y;
                  st.z = slot[2*j+1].x; st.w = slot[2*j+1].y;
        dst[j] = st;
    }
}

// ---------------- gather pass: one thread per ray ----------------------------
__global__ __launch_bounds__(256) void gather_kernel(
    const uint2* __restrict__ packed,
    const int*   __restrict__ vidx,
    const float* __restrict__ ipos,
    const float* __restrict__ vmin,
    const int*   __restrict__ mask,
    float*       __restrict__ out,
    int n)
{
    int i = blockIdx.x * blockDim.x + threadIdx.x;
    if (i >= n) return;

    int x = vidx[3*i+0];
    int y = vidx[3*i+1];
    int z = vidx[3*i+2];

    float tx = (ipos[3*i+0] - vmin[3*i+0]) * INV_VS;
    float ty = (ipos[3*i+1] - vmin[3*i+1]) * INV_VS;
    float tz = (ipos[3*i+2] - vmin[3*i+2]) * INV_VS;

    int   m   = mask[i];
    float inv = 1.0f - (float)m;

    float ox = 1.0f - tx, oy = 1.0f - ty, oz = 1.0f - tz;
    // corner order k = dx*4 + dy*2 + dz — matches reference
    float w[8];
    w[0] = oz*oy*ox;  w[1] = tz*oy*ox;  w[2] = oz*ty*ox;  w[3] = tz*ty*ox;
    w[4] = oz*oy*tx;  w[5] = tz*oy*tx;  w[6] = oz*ty*tx;  w[7] = tz*ty*tx;

    float accx = 0.f, accy = 0.f, accz = 0.f;
    float gbase = 0.f;

    #pragma unroll
    for (int k = 0; k < 8; ++k) {
        int cx = x + (k >> 2), cy = y + ((k >> 1) & 1), cz = z + (k & 1);
        int B  = ((cx >> 1)*NBRK + (cy >> 1))*NBRK + (cz >> 1);
        int s  = (cx & 1)*4 + (cy & 1)*2 + (cz & 1);
        uint2 p = packed[B*8 + s];
        accx += h2f(p.x & 0xffff) * w[k];
        accy += h2f(p.x >> 16)    * w[k];
        accz += h2f(p.y & 0xffff) * w[k];
        if (k == 0) gbase = h2f(p.y >> 16);
    }

    float4 o;
    o.x = accx + inv;   // +(1-m) on all 8 corners distributes out (sum w = 1)
    o.y = accy + inv;
    o.z = accz + inv;
    o.w = fmaxf(-gbase, 0.0f) * (float)m;
    *reinterpret_cast<float4*>(out + 4*i) = o;
}

// ---------------- fallback: direct on-the-fly kernel -------------------------
__global__ __launch_bounds__(256) void sdf_grid_kernel(
    const float* __restrict__ grid,
    const int*   __restrict__ vidx,
    const float* __restrict__ ipos,
    const float* __restrict__ vmin,
    const int*   __restrict__ mask,
    float*       __restrict__ out,
    int n)
{
    int i = blockIdx.x * blockDim.x + threadIdx.x;
    if (i >= n) return;
    int x = vidx[3*i+0], y = vidx[3*i+1], z = vidx[3*i+2];
    float tx = (ipos[3*i+0] - vmin[3*i+0]) * INV_VS;
    float ty = (ipos[3*i+1] - vmin[3*i+1]) * INV_VS;
    float tz = (ipos[3*i+2] - vmin[3*i+2]) * INV_VS;
    int   m   = mask[i];
    float inv = 1.0f - (float)m;
    float ox = 1.0f - tx, oy = 1.0f - ty, oz = 1.0f - tz;
    float w[8];
    w[0] = oz*oy*ox;  w[1] = tz*oy*ox;  w[2] = oz*ty*ox;  w[3] = tz*ty*ox;
    w[4] = oz*oy*tx;  w[5] = tz*oy*tx;  w[6] = oz*ty*tx;  w[7] = tz*ty*tx;
    int base = z + GRID_R*y + GRID_RR*x;
    float nout[3];
    #pragma unroll
    for (int a = 0; a < 3; ++a) {
        const int s  = (a==0) ? GRID_RR : (a==1) ? GRID_R : 1;
        const int c0 = (a==0) ? x : (a==1) ? y : z;
        float acc = 0.0f;
        #pragma unroll
        for (int k = 0; k < 8; ++k) {
            const int dx = k>>2, dy = (k>>1)&1, dz = k&1;
            const int b  = base + dz + GRID_R*dy + GRID_RR*dx;
            const int cc = c0 + ((a==0) ? dx : (a==1) ? dy : dz);
            float v;
            if (cc == 0)            v = grid[b+s] - (3.0f*grid[b] - grid[b+2*s])*0.5f;
            else if (cc == GRID_R-1) v = (3.0f*grid[b] - grid[b-2*s])*0.5f - grid[b-s];
            else                    v = grid[b+s] - grid[b-s];
            acc += (v*INV_2VS + inv) * w[k];
        }
        nout[a] = acc;
    }
    float gx = fmaxf(-grid[base], 0.0f) * (float)m;
    float4 o; o.x = nout[0]; o.y = nout[1]; o.z = nout[2]; o.w = gx;
    *reinterpret_cast<float4*>(out + 4*i) = o;
}

extern "C" void kernel_launch(void* const* d_in, const int* in_sizes, int n_in,
                              void* d_out, int out_size, void* d_ws, size_t ws_size,
                              hipStream_t stream) {
    const float* grid = (const float*)d_in[0];
    const int*   vidx = (const int*)d_in[1];
    const float* ipos = (const float*)d_in[2];
    const float* vmin = (const float*)d_in[3];
    const int*   mask = (const int*)d_in[4];
    float*       out  = (float*)d_out;

    const int n = in_sizes[4];          // H*W rays
    const int block = 256;

    if (ws_size >= (size_t)NVOX * 8) {
        uint2* packed = (uint2*)d_ws;
        // 128^3 bricks / (256 threads * 1 brick each) = 8192 blocks
        precompute_brick_kernel<<<8192, block, 0, stream>>>(grid, packed);
        gather_kernel<<<(n + block - 1) / block, block, 0, stream>>>(
            packed, vidx, ipos, vmin, mask, out, n);
    } else {
        sdf_grid_kernel<<<(n + block - 1) / block, block, 0, stream>>>(
            grid, vidx, ipos, vmin, mask, out, n);
    }
}